// Round 1
// baseline (521.878 us; speedup 1.0000x reference)
//
#include <hip/hip_runtime.h>
#include <stdint.h>
#include <stddef.h>

#define DEV __device__ __forceinline__

typedef __bf16 bf16_t;
typedef bf16_t bf16x8 __attribute__((ext_vector_type(8)));
typedef float f32x4 __attribute__((ext_vector_type(4)));
typedef unsigned short us4 __attribute__((ext_vector_type(4)));
typedef unsigned short us8 __attribute__((ext_vector_type(8)));

// ---------- bf16 <-> f32 helpers (bit-level, RNE) ----------
DEV float bf2f(unsigned short u) {
    union { unsigned int i; float f; } w; w.i = ((unsigned int)u) << 16; return w.f;
}
DEV unsigned short f2bf(float f) {
    union { unsigned int i; float f; } w; w.f = f;
    unsigned int u = w.i;
    return (unsigned short)((u + 0x7fffu + ((u >> 16) & 1u)) >> 16);
}

// ---------- async global -> LDS, 16B per lane ----------
DEV void gl_lds16(const void* g, void* l) {
    __builtin_amdgcn_global_load_lds((const __attribute__((address_space(1))) void*)g,
                                     (__attribute__((address_space(3))) void*)l,
                                     16, 0, 0);
}

// ======================================================================
// fp32 -> bf16 convert, 3 tensors in one dispatch (z selects)
// ======================================================================
__global__ void __launch_bounds__(256)
cvt3(const float* __restrict__ s0, const float* __restrict__ s1, const float* __restrict__ s2,
     unsigned short* __restrict__ d0, unsigned short* __restrict__ d1, unsigned short* __restrict__ d2) {
    const float* src    = (blockIdx.z == 0) ? s0 : (blockIdx.z == 1) ? s1 : s2;
    unsigned short* dst = (blockIdx.z == 0) ? d0 : (blockIdx.z == 1) ? d1 : d2;
    int idx = (blockIdx.x * 256 + threadIdx.x) * 4;
    f32x4 v = *(const f32x4*)&src[idx];
    us4 o;
#pragma unroll
    for (int i = 0; i < 4; i++) o[i] = f2bf(v[i]);
    *(us4*)&dst[idx] = o;
}

// ======================================================================
// Weight transpose+convert: W fp32 (1024x1024 KxN) -> WT bf16 (NxK)
// ======================================================================
__global__ void __launch_bounds__(256)
transpose_w(const float* __restrict__ W0, const float* __restrict__ W1,
            const float* __restrict__ W2, const float* __restrict__ W3,
            unsigned short* __restrict__ T0, unsigned short* __restrict__ T1,
            unsigned short* __restrict__ T2, unsigned short* __restrict__ T3) {
    const float* W    = (blockIdx.z == 0) ? W0 : (blockIdx.z == 1) ? W1 : (blockIdx.z == 2) ? W2 : W3;
    unsigned short* T = (blockIdx.z == 0) ? T0 : (blockIdx.z == 1) ? T1 : (blockIdx.z == 2) ? T2 : T3;
    __shared__ float t[32][33];
    int tx = threadIdx.x, ty = threadIdx.y;       // 32 x 8
    int k0 = blockIdx.x * 32, n0 = blockIdx.y * 32;
#pragma unroll
    for (int r = 0; r < 4; r++)
        t[ty + r * 8][tx] = W[(size_t)(k0 + ty + r * 8) * 1024 + n0 + tx];
    __syncthreads();
#pragma unroll
    for (int r = 0; r < 4; r++)
        T[(size_t)(n0 + ty + r * 8) * 1024 + k0 + tx] = f2bf(t[tx][ty + r * 8]);
}

// ======================================================================
// Fused Q/K/V projection: z picks (A, Bt, bias, out, mode).
// 128x128 tile, BK=32, 4 waves each 64x64, mfma 16x16x32 bf16.
// z=0,1: bf16 split-head (B,H,S,D);  z=2: bf16 (B,H,D,S) for V
// ======================================================================
__global__ void __launch_bounds__(256)
qkv_gemm(const unsigned short* __restrict__ Aq, const unsigned short* __restrict__ Ak,
         const unsigned short* __restrict__ Av,
         const unsigned short* __restrict__ BtQ, const unsigned short* __restrict__ BtK,
         const unsigned short* __restrict__ BtV,
         const float* __restrict__ biq, const float* __restrict__ bik,
         const float* __restrict__ biv,
         unsigned short* __restrict__ Qw, unsigned short* __restrict__ Kw,
         unsigned short* __restrict__ Vtw) {
    const int K = 1024;
    const unsigned short* A  = (blockIdx.z == 0) ? Aq  : (blockIdx.z == 1) ? Ak  : Av;
    const unsigned short* Bt = (blockIdx.z == 0) ? BtQ : (blockIdx.z == 1) ? BtK : BtV;
    const float* bias        = (blockIdx.z == 0) ? biq : (blockIdx.z == 1) ? bik : biv;
    unsigned short* Cout     = (blockIdx.z == 0) ? Qw  : (blockIdx.z == 1) ? Kw  : Vtw;
    const bool vmode = (blockIdx.z == 2);

    __shared__ __align__(16) unsigned short As[128 * 32];
    __shared__ __align__(16) unsigned short Bs[128 * 32];
    int tid = threadIdx.x, lane = tid & 63, wid = tid >> 6;
    int mBase = blockIdx.x * 128, nBase = blockIdx.y * 128;
    int wm = (wid >> 1) * 64, wn = (wid & 1) * 64;
    int c0 = lane & 15, quad = lane >> 4;

    f32x4 acc[4][4] = {};

    for (int k0 = 0; k0 < K; k0 += 32) {
        __syncthreads();
#pragma unroll
        for (int i = 0; i < 2; i++) {
            int cb = wid * 64 + 256 * i;
            int cc = cb + lane;
            int row = cc >> 2, kc = cc & 3;
            gl_lds16(A  + (size_t)(mBase + row) * K + k0 + kc * 8, &As[cb * 8]);
            gl_lds16(Bt + (size_t)(nBase + row) * K + k0 + kc * 8, &Bs[cb * 8]);
        }
        __syncthreads();
        bf16x8 af[4], bfr[4];
#pragma unroll
        for (int t = 0; t < 4; t++) {
            af[t]  = *(const bf16x8*)&As[(wm + t * 16 + c0) * 32 + quad * 8];
            bfr[t] = *(const bf16x8*)&Bs[(wn + t * 16 + c0) * 32 + quad * 8];
        }
#pragma unroll
        for (int mt = 0; mt < 4; mt++)
#pragma unroll
            for (int nt = 0; nt < 4; nt++)
                acc[mt][nt] = __builtin_amdgcn_mfma_f32_16x16x32_bf16(af[mt], bfr[nt], acc[mt][nt], 0, 0, 0);
    }

    // C/D layout: col = lane&15, row = quad*4 + reg
#pragma unroll
    for (int mt = 0; mt < 4; mt++) {
#pragma unroll
        for (int nt = 0; nt < 4; nt++) {
            int n = nBase + wn + nt * 16 + c0;
            float bv = bias[n];
            if (vmode) {
                int m0 = mBase + wm + mt * 16 + quad * 4;
                int b = m0 >> 10, s = m0 & 1023, h = n >> 6, d = n & 63;
                us4 pk;
#pragma unroll
                for (int r = 0; r < 4; r++) pk[r] = f2bf(acc[mt][nt][r] + bv);
                *(us4*)&Cout[((size_t)((b * 16 + h) * 64 + d)) * 1024 + s] = pk;
            } else {
#pragma unroll
                for (int r = 0; r < 4; r++) {
                    int m = mBase + wm + mt * 16 + quad * 4 + r;
                    int b = m >> 10, s = m & 1023, h = n >> 6, d = n & 63;
                    Cout[((size_t)((b * 16 + h) * 1024 + s)) * 64 + d] = f2bf(acc[mt][nt][r] + bv);
                }
            }
        }
    }
}

// ======================================================================
// Final projection: C = ctx @ WoT^T + bo -> fp32 (M,1024)
// ======================================================================
__global__ void __launch_bounds__(256)
out_gemm(const unsigned short* __restrict__ A,
         const unsigned short* __restrict__ Bt,
         const float* __restrict__ bias,
         float* __restrict__ Cout) {
    const int K = 1024;
    __shared__ __align__(16) unsigned short As[128 * 32];
    __shared__ __align__(16) unsigned short Bs[128 * 32];
    int tid = threadIdx.x, lane = tid & 63, wid = tid >> 6;
    int mBase = blockIdx.x * 128, nBase = blockIdx.y * 128;
    int wm = (wid >> 1) * 64, wn = (wid & 1) * 64;
    int c0 = lane & 15, quad = lane >> 4;

    f32x4 acc[4][4] = {};

    for (int k0 = 0; k0 < K; k0 += 32) {
        __syncthreads();
#pragma unroll
        for (int i = 0; i < 2; i++) {
            int cb = wid * 64 + 256 * i;
            int cc = cb + lane;
            int row = cc >> 2, kc = cc & 3;
            gl_lds16(A  + (size_t)(mBase + row) * K + k0 + kc * 8, &As[cb * 8]);
            gl_lds16(Bt + (size_t)(nBase + row) * K + k0 + kc * 8, &Bs[cb * 8]);
        }
        __syncthreads();
        bf16x8 af[4], bfr[4];
#pragma unroll
        for (int t = 0; t < 4; t++) {
            af[t]  = *(const bf16x8*)&As[(wm + t * 16 + c0) * 32 + quad * 8];
            bfr[t] = *(const bf16x8*)&Bs[(wn + t * 16 + c0) * 32 + quad * 8];
        }
#pragma unroll
        for (int mt = 0; mt < 4; mt++)
#pragma unroll
            for (int nt = 0; nt < 4; nt++)
                acc[mt][nt] = __builtin_amdgcn_mfma_f32_16x16x32_bf16(af[mt], bfr[nt], acc[mt][nt], 0, 0, 0);
    }
#pragma unroll
    for (int mt = 0; mt < 4; mt++)
#pragma unroll
        for (int nt = 0; nt < 4; nt++) {
            int n = nBase + wn + nt * 16 + c0;
            float bv = bias[n];
#pragma unroll
            for (int r = 0; r < 4; r++) {
                int m = mBase + wm + mt * 16 + quad * 4 + r;
                Cout[(size_t)m * 1024 + n] = acc[mt][nt][r] + bv;
            }
        }
}

// ======================================================================
// Fused QK^T/64 + mask + softmax + attn-write (fp32) + PV -> ctx (bf16)
// One block = 16 q-rows of one (b,h).  P kept on-chip (regs -> LDS).
// K and V are L2-resident (128KB each per bh, re-read by 64 blocks):
// read MFMA B-fragments DIRECTLY from global (no LDS staging, no
// staging barriers).  LDS holds only the P exchange buffer (35KB)
// -> 3 blocks/CU instead of 2, and phases 1/4 are barrier-free.
//   Phase 1: QK^T, logits in regs (16 frags/wave, wave w owns cols
//            ch*256 + w*64 + nt*16 + c0), K frags direct from global
//   Phase 2: softmax (shuffle + LDS reduce)
//   Phase 3: write attn fp32 to global (nontemporal; 256MB stream must
//            not thrash K/V out of L2); write P bf16 to LDS in A-layout
//            P_lds[wv][row][kk], kk = ch*64+nt*16+c0, stride 272,
//            chunk XOR-swizzle by (row>>2) for bank spread
//   Phase 4: PV: wave w computes ctx[0:16][w*16 : w*16+16] over all k;
//            V frags direct from global (Vt layout), 2 accumulators
// ======================================================================
__global__ void __launch_bounds__(256, 3)
attn_pv(const unsigned short* __restrict__ Qws,
        const unsigned short* __restrict__ Kws,
        const unsigned short* __restrict__ Vtw,
        const float* __restrict__ maskp,
        float* __restrict__ attnOut,
        unsigned short* __restrict__ ctx) {
    __shared__ __align__(16) unsigned short ldsP[17408]; // 4 regions x 16 rows x 272
    __shared__ float redbuf[4][16];

    int tid = threadIdx.x, lane = tid & 63, wid = tid >> 6;
    int c0 = lane & 15, quad = lane >> 4;
    int bh = blockIdx.y, b = bh >> 4, h = bh & 15;
    int q0 = blockIdx.x * 16;

    // Q A-fragments
    bf16x8 aq0, aq1;
    {
        const unsigned short* qp = Qws + ((size_t)bh * 1024 + q0 + c0) * 64 + quad * 8;
        aq0 = *(const bf16x8*)qp;
        aq1 = *(const bf16x8*)(qp + 32);
    }

    f32x4 acc[16] = {};

    // ---- Phase 1: QK^T (K B-frags direct from global/L2, no barriers) ----
    const unsigned short* kbase = Kws + (size_t)bh * 1024 * 64;
#pragma unroll
    for (int ch = 0; ch < 4; ch++) {
#pragma unroll
        for (int nt = 0; nt < 4; nt++) {
            int srow = ch * 256 + wid * 64 + nt * 16 + c0;
            const unsigned short* kp = kbase + (size_t)srow * 64 + quad * 8;
            bf16x8 b0 = *(const bf16x8*)kp;
            bf16x8 b1 = *(const bf16x8*)(kp + 32);
            int ai = ch * 4 + nt;
            acc[ai] = __builtin_amdgcn_mfma_f32_16x16x32_bf16(aq0, b0, acc[ai], 0, 0, 0);
            acc[ai] = __builtin_amdgcn_mfma_f32_16x16x32_bf16(aq1, b1, acc[ai], 0, 0, 0);
        }
    }

    // ---- Phase 2: softmax ----
    float lmax[4] = {-3e38f, -3e38f, -3e38f, -3e38f};
#pragma unroll
    for (int i = 0; i < 16; i++) {
        int col = (i >> 2) * 256 + wid * 64 + (i & 3) * 16 + c0;
        float mval = maskp[b * 1024 + col] * (-1e9f);
#pragma unroll
        for (int r = 0; r < 4; r++) {
            float v = acc[i][r] * (1.0f / 64.0f) + mval;
            acc[i][r] = v;
            lmax[r] = fmaxf(lmax[r], v);
        }
    }
#pragma unroll
    for (int st = 1; st < 16; st <<= 1) {
#pragma unroll
        for (int r = 0; r < 4; r++) lmax[r] = fmaxf(lmax[r], __shfl_xor(lmax[r], st, 64));
    }
    if (c0 == 0) {
#pragma unroll
        for (int r = 0; r < 4; r++) redbuf[wid][quad * 4 + r] = lmax[r];
    }
    __syncthreads();
    float rmax[4];
#pragma unroll
    for (int r = 0; r < 4; r++) {
        int row = quad * 4 + r;
        rmax[r] = fmaxf(fmaxf(redbuf[0][row], redbuf[1][row]), fmaxf(redbuf[2][row], redbuf[3][row]));
    }
    float lsum[4] = {0.f, 0.f, 0.f, 0.f};
#pragma unroll
    for (int i = 0; i < 16; i++) {
#pragma unroll
        for (int r = 0; r < 4; r++) {
            float e = __expf(acc[i][r] - rmax[r]);
            acc[i][r] = e;
            lsum[r] += e;
        }
    }
#pragma unroll
    for (int st = 1; st < 16; st <<= 1) {
#pragma unroll
        for (int r = 0; r < 4; r++) lsum[r] += __shfl_xor(lsum[r], st, 64);
    }
    __syncthreads();
    if (c0 == 0) {
#pragma unroll
        for (int r = 0; r < 4; r++) redbuf[wid][quad * 4 + r] = lsum[r];
    }
    __syncthreads();
    float rinv[4];
#pragma unroll
    for (int r = 0; r < 4; r++) {
        int row = quad * 4 + r;
        rinv[r] = 1.0f / (redbuf[0][row] + redbuf[1][row] + redbuf[2][row] + redbuf[3][row]);
    }

    // ---- Phase 3: attn global write (fp32, nontemporal) + P -> LDS ----
    size_t gbase = ((size_t)bh * 1024 + q0) * 1024;
#pragma unroll
    for (int i = 0; i < 16; i++) {
        int kk = (i >> 2) * 64 + (i & 3) * 16 + c0;
        int col = (i >> 2) * 256 + wid * 64 + (i & 3) * 16 + c0;
        int kks = kk ^ (quad << 3);   // row>>2 == quad for all 4 regs
#pragma unroll
        for (int r = 0; r < 4; r++) {
            int row = quad * 4 + r;
            float pv = acc[i][r] * rinv[r];
            __builtin_nontemporal_store(pv, &attnOut[gbase + (size_t)row * 1024 + col]);
            ldsP[wid * 4352 + row * 272 + kks] = f2bf(pv);
        }
    }
    __syncthreads();

    // ---- Phase 4: PV (V B-frags direct from global/L2, no barriers) ----
    f32x4 ctx0 = {}, ctx1 = {};
    const unsigned short* vbase = Vtw + ((size_t)(bh * 64 + wid * 16 + c0)) * 1024 + quad * 8;
#pragma unroll
    for (int ch = 0; ch < 4; ch++) {
#pragma unroll
        for (int wv = 0; wv < 4; wv++) {
            int kidx0 = (ch * 64 + quad * 8) ^ ((c0 >> 2) << 3);
            int kidx1 = (ch * 64 + 32 + quad * 8) ^ ((c0 >> 2) << 3);
            bf16x8 a0 = *(const bf16x8*)&ldsP[wv * 4352 + c0 * 272 + kidx0];
            bf16x8 a1 = *(const bf16x8*)&ldsP[wv * 4352 + c0 * 272 + kidx1];
            bf16x8 v0 = *(const bf16x8*)&vbase[ch * 256 + wv * 64];
            bf16x8 v1 = *(const bf16x8*)&vbase[ch * 256 + wv * 64 + 32];
            ctx0 = __builtin_amdgcn_mfma_f32_16x16x32_bf16(a0, v0, ctx0, 0, 0, 0);
            ctx1 = __builtin_amdgcn_mfma_f32_16x16x32_bf16(a1, v1, ctx1, 0, 0, 0);
        }
    }
    f32x4 ctxacc = ctx0 + ctx1;

    // ctx write: C-layout frag, rows=q, cols = wid*16+c0 (d)
#pragma unroll
    for (int r = 0; r < 4; r++) {
        int s = q0 + quad * 4 + r;
        ctx[((size_t)(b * 1024 + s)) * 1024 + h * 64 + wid * 16 + c0] = f2bf(ctxacc[r]);
    }
}

// ======================================================================
// host
// ======================================================================
extern "C" void kernel_launch(void* const* d_in, const int* in_sizes, int n_in,
                              void* d_out, int out_size, void* d_ws, size_t ws_size,
                              hipStream_t stream) {
    (void)in_sizes; (void)n_in; (void)out_size; (void)ws_size;
    const float* q    = (const float*)d_in[0];
    const float* k    = (const float*)d_in[1];
    const float* v    = (const float*)d_in[2];
    const float* mask = (const float*)d_in[3];
    const float* Wq   = (const float*)d_in[4];
    const float* bq   = (const float*)d_in[5];
    const float* Wk   = (const float*)d_in[6];
    const float* bk   = (const float*)d_in[7];
    const float* Wv   = (const float*)d_in[8];
    const float* bv   = (const float*)d_in[9];
    const float* Wo   = (const float*)d_in[10];
    const float* bo   = (const float*)d_in[11];

    float* outF  = (float*)d_out;                          // (B,S,1024): 4M floats
    float* attnF = outF + (size_t)4 * 1024 * 1024;         // (B,H,S,S): 64M floats

    unsigned short* wsu = (unsigned short*)d_ws;
    const size_t M1 = (size_t)1024 * 1024;
    unsigned short* WqT = wsu + 0 * M1;
    unsigned short* WkT = wsu + 1 * M1;
    unsigned short* WvT = wsu + 2 * M1;
    unsigned short* WoT = wsu + 3 * M1;
    unsigned short* tq  = wsu + 4 * M1;        // 4M each
    unsigned short* tk  = wsu + 8 * M1;
    unsigned short* tv  = wsu + 12 * M1;
    unsigned short* Qw  = wsu + 16 * M1;       // (B,H,S,D)
    unsigned short* Kw  = wsu + 20 * M1;
    unsigned short* Vtw = wsu + 24 * M1;       // (B,H,D,S)
    unsigned short* ctx = wsu + 28 * M1;       // (B,S,H*D)  -> 64MB total

    transpose_w<<<dim3(32, 32, 4), dim3(32, 8), 0, stream>>>(Wq, Wk, Wv, Wo, WqT, WkT, WvT, WoT);

    cvt3<<<dim3(4096, 1, 3), 256, 0, stream>>>(q, k, v, tq, tk, tv);

    qkv_gemm<<<dim3(32, 8, 3), 256, 0, stream>>>(tq, tk, tv, WqT, WkT, WvT, bq, bk, bv, Qw, Kw, Vtw);

    attn_pv<<<dim3(64, 64), 256, 0, stream>>>(Qw, Kw, Vtw, mask, attnF, ctx);

    out_gemm<<<dim3(32, 8), 256, 0, stream>>>(ctx, WoT, bo, outF);
}

// Round 3
// 494.274 us; speedup vs baseline: 1.0558x; 1.0558x over previous
//
#include <hip/hip_runtime.h>
#include <stdint.h>
#include <stddef.h>

#define DEV __device__ __forceinline__

typedef __bf16 bf16_t;
typedef bf16_t bf16x8 __attribute__((ext_vector_type(8)));
typedef float f32x4 __attribute__((ext_vector_type(4)));
typedef unsigned short us4 __attribute__((ext_vector_type(4)));
typedef unsigned short us8 __attribute__((ext_vector_type(8)));

// ---------- bf16 <-> f32 helpers (bit-level, RNE) ----------
DEV float bf2f(unsigned short u) {
    union { unsigned int i; float f; } w; w.i = ((unsigned int)u) << 16; return w.f;
}
DEV unsigned short f2bf(float f) {
    union { unsigned int i; float f; } w; w.f = f;
    unsigned int u = w.i;
    return (unsigned short)((u + 0x7fffu + ((u >> 16) & 1u)) >> 16);
}

// ---------- async global -> LDS, 16B per lane ----------
DEV void gl_lds16(const void* g, void* l) {
    __builtin_amdgcn_global_load_lds((const __attribute__((address_space(1))) void*)g,
                                     (__attribute__((address_space(3))) void*)l,
                                     16, 0, 0);
}

// ======================================================================
// fp32 -> bf16 convert, 3 tensors in one dispatch (z selects)
// ======================================================================
__global__ void __launch_bounds__(256)
cvt3(const float* __restrict__ s0, const float* __restrict__ s1, const float* __restrict__ s2,
     unsigned short* __restrict__ d0, unsigned short* __restrict__ d1, unsigned short* __restrict__ d2) {
    const float* src    = (blockIdx.z == 0) ? s0 : (blockIdx.z == 1) ? s1 : s2;
    unsigned short* dst = (blockIdx.z == 0) ? d0 : (blockIdx.z == 1) ? d1 : d2;
    int idx = (blockIdx.x * 256 + threadIdx.x) * 4;
    f32x4 v = *(const f32x4*)&src[idx];
    us4 o;
#pragma unroll
    for (int i = 0; i < 4; i++) o[i] = f2bf(v[i]);
    *(us4*)&dst[idx] = o;
}

// ======================================================================
// Weight transpose+convert: W fp32 (1024x1024 KxN) -> WT bf16 (NxK)
// ======================================================================
__global__ void __launch_bounds__(256)
transpose_w(const float* __restrict__ W0, const float* __restrict__ W1,
            const float* __restrict__ W2, const float* __restrict__ W3,
            unsigned short* __restrict__ T0, unsigned short* __restrict__ T1,
            unsigned short* __restrict__ T2, unsigned short* __restrict__ T3) {
    const float* W    = (blockIdx.z == 0) ? W0 : (blockIdx.z == 1) ? W1 : (blockIdx.z == 2) ? W2 : W3;
    unsigned short* T = (blockIdx.z == 0) ? T0 : (blockIdx.z == 1) ? T1 : (blockIdx.z == 2) ? T2 : T3;
    __shared__ float t[32][33];
    int tx = threadIdx.x, ty = threadIdx.y;       // 32 x 8
    int k0 = blockIdx.x * 32, n0 = blockIdx.y * 32;
#pragma unroll
    for (int r = 0; r < 4; r++)
        t[ty + r * 8][tx] = W[(size_t)(k0 + ty + r * 8) * 1024 + n0 + tx];
    __syncthreads();
#pragma unroll
    for (int r = 0; r < 4; r++)
        T[(size_t)(n0 + ty + r * 8) * 1024 + k0 + tx] = f2bf(t[tx][ty + r * 8]);
}

// ======================================================================
// Fused Q/K/V projection: z picks (A, Bt, bias, out, mode).
// 128x128 tile, BK=32, 4 waves each 64x64, mfma 16x16x32 bf16.
// z=0,1: bf16 split-head (B,H,S,D);  z=2: bf16 (B,H,D,S) for V
// ======================================================================
__global__ void __launch_bounds__(256)
qkv_gemm(const unsigned short* __restrict__ Aq, const unsigned short* __restrict__ Ak,
         const unsigned short* __restrict__ Av,
         const unsigned short* __restrict__ BtQ, const unsigned short* __restrict__ BtK,
         const unsigned short* __restrict__ BtV,
         const float* __restrict__ biq, const float* __restrict__ bik,
         const float* __restrict__ biv,
         unsigned short* __restrict__ Qw, unsigned short* __restrict__ Kw,
         unsigned short* __restrict__ Vtw) {
    const int K = 1024;
    const unsigned short* A  = (blockIdx.z == 0) ? Aq  : (blockIdx.z == 1) ? Ak  : Av;
    const unsigned short* Bt = (blockIdx.z == 0) ? BtQ : (blockIdx.z == 1) ? BtK : BtV;
    const float* bias        = (blockIdx.z == 0) ? biq : (blockIdx.z == 1) ? bik : biv;
    unsigned short* Cout     = (blockIdx.z == 0) ? Qw  : (blockIdx.z == 1) ? Kw  : Vtw;
    const bool vmode = (blockIdx.z == 2);

    __shared__ __align__(16) unsigned short As[128 * 32];
    __shared__ __align__(16) unsigned short Bs[128 * 32];
    int tid = threadIdx.x, lane = tid & 63, wid = tid >> 6;
    int mBase = blockIdx.x * 128, nBase = blockIdx.y * 128;
    int wm = (wid >> 1) * 64, wn = (wid & 1) * 64;
    int c0 = lane & 15, quad = lane >> 4;

    f32x4 acc[4][4] = {};

    for (int k0 = 0; k0 < K; k0 += 32) {
        __syncthreads();
#pragma unroll
        for (int i = 0; i < 2; i++) {
            int cb = wid * 64 + 256 * i;
            int cc = cb + lane;
            int row = cc >> 2, kc = cc & 3;
            gl_lds16(A  + (size_t)(mBase + row) * K + k0 + kc * 8, &As[cb * 8]);
            gl_lds16(Bt + (size_t)(nBase + row) * K + k0 + kc * 8, &Bs[cb * 8]);
        }
        __syncthreads();
        bf16x8 af[4], bfr[4];
#pragma unroll
        for (int t = 0; t < 4; t++) {
            af[t]  = *(const bf16x8*)&As[(wm + t * 16 + c0) * 32 + quad * 8];
            bfr[t] = *(const bf16x8*)&Bs[(wn + t * 16 + c0) * 32 + quad * 8];
        }
#pragma unroll
        for (int mt = 0; mt < 4; mt++)
#pragma unroll
            for (int nt = 0; nt < 4; nt++)
                acc[mt][nt] = __builtin_amdgcn_mfma_f32_16x16x32_bf16(af[mt], bfr[nt], acc[mt][nt], 0, 0, 0);
    }

    // C/D layout: col = lane&15, row = quad*4 + reg
#pragma unroll
    for (int mt = 0; mt < 4; mt++) {
#pragma unroll
        for (int nt = 0; nt < 4; nt++) {
            int n = nBase + wn + nt * 16 + c0;
            float bv = bias[n];
            if (vmode) {
                int m0 = mBase + wm + mt * 16 + quad * 4;
                int b = m0 >> 10, s = m0 & 1023, h = n >> 6, d = n & 63;
                us4 pk;
#pragma unroll
                for (int r = 0; r < 4; r++) pk[r] = f2bf(acc[mt][nt][r] + bv);
                *(us4*)&Cout[((size_t)((b * 16 + h) * 64 + d)) * 1024 + s] = pk;
            } else {
#pragma unroll
                for (int r = 0; r < 4; r++) {
                    int m = mBase + wm + mt * 16 + quad * 4 + r;
                    int b = m >> 10, s = m & 1023, h = n >> 6, d = n & 63;
                    Cout[((size_t)((b * 16 + h) * 1024 + s)) * 64 + d] = f2bf(acc[mt][nt][r] + bv);
                }
            }
        }
    }
}

// ======================================================================
// Final projection: C = ctx @ WoT^T + bo -> fp32 (M,1024)
// ======================================================================
__global__ void __launch_bounds__(256)
out_gemm(const unsigned short* __restrict__ A,
         const unsigned short* __restrict__ Bt,
         const float* __restrict__ bias,
         float* __restrict__ Cout) {
    const int K = 1024;
    __shared__ __align__(16) unsigned short As[128 * 32];
    __shared__ __align__(16) unsigned short Bs[128 * 32];
    int tid = threadIdx.x, lane = tid & 63, wid = tid >> 6;
    int mBase = blockIdx.x * 128, nBase = blockIdx.y * 128;
    int wm = (wid >> 1) * 64, wn = (wid & 1) * 64;
    int c0 = lane & 15, quad = lane >> 4;

    f32x4 acc[4][4] = {};

    for (int k0 = 0; k0 < K; k0 += 32) {
        __syncthreads();
#pragma unroll
        for (int i = 0; i < 2; i++) {
            int cb = wid * 64 + 256 * i;
            int cc = cb + lane;
            int row = cc >> 2, kc = cc & 3;
            gl_lds16(A  + (size_t)(mBase + row) * K + k0 + kc * 8, &As[cb * 8]);
            gl_lds16(Bt + (size_t)(nBase + row) * K + k0 + kc * 8, &Bs[cb * 8]);
        }
        __syncthreads();
        bf16x8 af[4], bfr[4];
#pragma unroll
        for (int t = 0; t < 4; t++) {
            af[t]  = *(const bf16x8*)&As[(wm + t * 16 + c0) * 32 + quad * 8];
            bfr[t] = *(const bf16x8*)&Bs[(wn + t * 16 + c0) * 32 + quad * 8];
        }
#pragma unroll
        for (int mt = 0; mt < 4; mt++)
#pragma unroll
            for (int nt = 0; nt < 4; nt++)
                acc[mt][nt] = __builtin_amdgcn_mfma_f32_16x16x32_bf16(af[mt], bfr[nt], acc[mt][nt], 0, 0, 0);
    }
#pragma unroll
    for (int mt = 0; mt < 4; mt++)
#pragma unroll
        for (int nt = 0; nt < 4; nt++) {
            int n = nBase + wn + nt * 16 + c0;
            float bv = bias[n];
#pragma unroll
            for (int r = 0; r < 4; r++) {
                int m = mBase + wm + mt * 16 + quad * 4 + r;
                Cout[(size_t)m * 1024 + n] = acc[mt][nt][r] + bv;
            }
        }
}

// ======================================================================
// Fused QK^T/64 + mask + softmax + attn-write (fp32) + PV -> ctx (bf16)
// One block = 16 q-rows of one (b,h).
//   Phase 1: QK^T via gl_lds-staged K chunks (256x64 = 32KB) [as r0]
//   Phase 2: softmax (shuffle + LDS reduce)                  [as r0]
//   Phase 3: attn fp32 store + P bf16 -> LDS (A-layout)      [as r0]
//            (acc dies here -> registers free for V prefetch)
//   Phase 4: PV; NO Vs buffer: V frags direct from global/L2 with a
//            full-chunk register prefetch (vcur/vnxt, 8 frags each).
//            Single barrier (P_lds ready); no per-chunk barriers; no
//            Vs 4-way LDS bank conflicts (row-stride-272 reads gone).
// LDS = 35.3KB (ldsP+redbuf) -> 3 blocks/CU (launch_bounds cap 168 VGPR,
// est. peak ~130, no spill; was 2 blocks/CU with the 34.8KB Vs buffer).
// ======================================================================
__global__ void __launch_bounds__(256, 3)
attn_pv(const unsigned short* __restrict__ Qws,
        const unsigned short* __restrict__ Kws,
        const unsigned short* __restrict__ Vtw,
        const float* __restrict__ maskp,
        float* __restrict__ attnOut,
        unsigned short* __restrict__ ctx) {
    __shared__ __align__(16) unsigned short ldsP[17408]; // Ks chunk (256x64) / P_lds (4*16*272)
    __shared__ float redbuf[4][16];

    int tid = threadIdx.x, lane = tid & 63, wid = tid >> 6;
    int c0 = lane & 15, quad = lane >> 4;
    int bh = blockIdx.y, b = bh >> 4, h = bh & 15;
    int q0 = blockIdx.x * 16;

    // Q A-fragments
    bf16x8 aq0, aq1;
    {
        const unsigned short* qp = Qws + ((size_t)bh * 1024 + q0 + c0) * 64 + quad * 8;
        aq0 = *(const bf16x8*)qp;
        aq1 = *(const bf16x8*)(qp + 32);
    }

    f32x4 acc[16] = {};

    // ---- Phase 1: QK^T (K staged via gl_lds, 4 chunks of 256 rows) ----
    for (int ch = 0; ch < 4; ch++) {
        __syncthreads();
#pragma unroll
        for (int i = 0; i < 8; i++) {
            int cb = wid * 64 + 256 * i;
            int cc = cb + lane;
            int row = cc >> 3, kc = cc & 7;
            gl_lds16(Kws + ((size_t)bh * 1024 + ch * 256 + row) * 64 + kc * 8, &ldsP[cb * 8]);
        }
        __syncthreads();
#pragma unroll
        for (int nt = 0; nt < 4; nt++) {
            int srow = wid * 64 + nt * 16 + c0;
            const unsigned short* kp = &ldsP[srow * 64 + quad * 8];
            bf16x8 b0 = *(const bf16x8*)kp;
            bf16x8 b1 = *(const bf16x8*)(kp + 32);
            int ai = ch * 4 + nt;
            acc[ai] = __builtin_amdgcn_mfma_f32_16x16x32_bf16(aq0, b0, acc[ai], 0, 0, 0);
            acc[ai] = __builtin_amdgcn_mfma_f32_16x16x32_bf16(aq1, b1, acc[ai], 0, 0, 0);
        }
    }

    // ---- Phase 2: softmax ----
    float lmax[4] = {-3e38f, -3e38f, -3e38f, -3e38f};
#pragma unroll
    for (int i = 0; i < 16; i++) {
        int col = (i >> 2) * 256 + wid * 64 + (i & 3) * 16 + c0;
        float mval = maskp[b * 1024 + col] * (-1e9f);
#pragma unroll
        for (int r = 0; r < 4; r++) {
            float v = acc[i][r] * (1.0f / 64.0f) + mval;
            acc[i][r] = v;
            lmax[r] = fmaxf(lmax[r], v);
        }
    }
#pragma unroll
    for (int st = 1; st < 16; st <<= 1) {
#pragma unroll
        for (int r = 0; r < 4; r++) lmax[r] = fmaxf(lmax[r], __shfl_xor(lmax[r], st, 64));
    }
    if (c0 == 0) {
#pragma unroll
        for (int r = 0; r < 4; r++) redbuf[wid][quad * 4 + r] = lmax[r];
    }
    __syncthreads();   // also guarantees all QK^T MFMAs done reading ldsP
    float rmax[4];
#pragma unroll
    for (int r = 0; r < 4; r++) {
        int row = quad * 4 + r;
        rmax[r] = fmaxf(fmaxf(redbuf[0][row], redbuf[1][row]), fmaxf(redbuf[2][row], redbuf[3][row]));
    }
    float lsum[4] = {0.f, 0.f, 0.f, 0.f};
#pragma unroll
    for (int i = 0; i < 16; i++) {
#pragma unroll
        for (int r = 0; r < 4; r++) {
            float e = __expf(acc[i][r] - rmax[r]);
            acc[i][r] = e;
            lsum[r] += e;
        }
    }
#pragma unroll
    for (int st = 1; st < 16; st <<= 1) {
#pragma unroll
        for (int r = 0; r < 4; r++) lsum[r] += __shfl_xor(lsum[r], st, 64);
    }
    __syncthreads();
    if (c0 == 0) {
#pragma unroll
        for (int r = 0; r < 4; r++) redbuf[wid][quad * 4 + r] = lsum[r];
    }
    __syncthreads();
    float rinv[4];
#pragma unroll
    for (int r = 0; r < 4; r++) {
        int row = quad * 4 + r;
        rinv[r] = 1.0f / (redbuf[0][row] + redbuf[1][row] + redbuf[2][row] + redbuf[3][row]);
    }

    // ---- Phase 3: attn global write (fp32) + P -> LDS (bf16, A-layout) ----
    size_t gbase = ((size_t)bh * 1024 + q0) * 1024;
#pragma unroll
    for (int i = 0; i < 16; i++) {
        int kk = (i >> 2) * 64 + (i & 3) * 16 + c0;
        int col = (i >> 2) * 256 + wid * 64 + (i & 3) * 16 + c0;
        int kks = kk ^ (quad << 3);   // row>>2 == quad for all 4 regs
#pragma unroll
        for (int r = 0; r < 4; r++) {
            int row = quad * 4 + r;
            float pv = acc[i][r] * rinv[r];
            attnOut[gbase + (size_t)row * 1024 + col] = pv;
            ldsP[wid * 4352 + row * 272 + kks] = f2bf(pv);
        }
    }

    // ---- Phase 4: PV (V direct from global/L2, 1-chunk-ahead prefetch) ----
    const unsigned short* vbase = Vtw + ((size_t)(bh * 64 + wid * 16 + c0)) * 1024 + quad * 8;
    bf16x8 vcur[8], vnxt[8];
#pragma unroll
    for (int j = 0; j < 8; j++)
        vcur[j] = *(const bf16x8*)&vbase[(j >> 1) * 64 + (j & 1) * 32];   // ch=0 frags
    __syncthreads();   // P_lds ready (cross-wave)

    f32x4 ctx0 = {}, ctx1 = {};
#pragma unroll
    for (int ch = 0; ch < 4; ch++) {
        if (ch < 3) {
#pragma unroll
            for (int j = 0; j < 8; j++)
                vnxt[j] = *(const bf16x8*)&vbase[(ch + 1) * 256 + (j >> 1) * 64 + (j & 1) * 32];
        }
#pragma unroll
        for (int wv = 0; wv < 4; wv++) {
            int kidx0 = (ch * 64 + quad * 8) ^ ((c0 >> 2) << 3);
            int kidx1 = (ch * 64 + 32 + quad * 8) ^ ((c0 >> 2) << 3);
            bf16x8 a0 = *(const bf16x8*)&ldsP[wv * 4352 + c0 * 272 + kidx0];
            bf16x8 a1 = *(const bf16x8*)&ldsP[wv * 4352 + c0 * 272 + kidx1];
            ctx0 = __builtin_amdgcn_mfma_f32_16x16x32_bf16(a0, vcur[wv * 2 + 0], ctx0, 0, 0, 0);
            ctx1 = __builtin_amdgcn_mfma_f32_16x16x32_bf16(a1, vcur[wv * 2 + 1], ctx1, 0, 0, 0);
        }
#pragma unroll
        for (int j = 0; j < 8; j++) vcur[j] = vnxt[j];
    }
    f32x4 ctxacc = ctx0 + ctx1;

    // ctx write: C-layout frag, rows=q, cols = wid*16+c0 (d)
#pragma unroll
    for (int r = 0; r < 4; r++) {
        int s = q0 + quad * 4 + r;
        ctx[((size_t)(b * 1024 + s)) * 1024 + h * 64 + wid * 16 + c0] = f2bf(ctxacc[r]);
    }
}

// ======================================================================
// host
// ======================================================================
extern "C" void kernel_launch(void* const* d_in, const int* in_sizes, int n_in,
                              void* d_out, int out_size, void* d_ws, size_t ws_size,
                              hipStream_t stream) {
    (void)in_sizes; (void)n_in; (void)out_size; (void)ws_size;
    const float* q    = (const float*)d_in[0];
    const float* k    = (const float*)d_in[1];
    const float* v    = (const float*)d_in[2];
    const float* mask = (const float*)d_in[3];
    const float* Wq   = (const float*)d_in[4];
    const float* bq   = (const float*)d_in[5];
    const float* Wk   = (const float*)d_in[6];
    const float* bk   = (const float*)d_in[7];
    const float* Wv   = (const float*)d_in[8];
    const float* bv   = (const float*)d_in[9];
    const float* Wo   = (const float*)d_in[10];
    const float* bo   = (const float*)d_in[11];

    float* outF  = (float*)d_out;                          // (B,S,1024): 4M floats
    float* attnF = outF + (size_t)4 * 1024 * 1024;         // (B,H,S,S): 64M floats

    unsigned short* wsu = (unsigned short*)d_ws;
    const size_t M1 = (size_t)1024 * 1024;
    unsigned short* WqT = wsu + 0 * M1;
    unsigned short* WkT = wsu + 1 * M1;
    unsigned short* WvT = wsu + 2 * M1;
    unsigned short* WoT = wsu + 3 * M1;
    unsigned short* tq  = wsu + 4 * M1;        // 4M each
    unsigned short* tk  = wsu + 8 * M1;
    unsigned short* tv  = wsu + 12 * M1;
    unsigned short* Qw  = wsu + 16 * M1;       // (B,H,S,D)
    unsigned short* Kw  = wsu + 20 * M1;
    unsigned short* Vtw = wsu + 24 * M1;       // (B,H,D,S)
    unsigned short* ctx = wsu + 28 * M1;       // (B,S,H*D)  -> 64MB total

    transpose_w<<<dim3(32, 32, 4), dim3(32, 8), 0, stream>>>(Wq, Wk, Wv, Wo, WqT, WkT, WvT, WoT);

    cvt3<<<dim3(4096, 1, 3), 256, 0, stream>>>(q, k, v, tq, tk, tv);

    qkv_gemm<<<dim3(32, 8, 3), 256, 0, stream>>>(tq, tk, tv, WqT, WkT, WvT, bq, bk, bv, Qw, Kw, Vtw);

    attn_pv<<<dim3(64, 64), 256, 0, stream>>>(Qw, Kw, Vtw, mask, attnF, ctx);

    out_gemm<<<dim3(32, 8), 256, 0, stream>>>(ctx, WoT, bo, outF);
}

// Round 4
// 475.081 us; speedup vs baseline: 1.0985x; 1.0404x over previous
//
#include <hip/hip_runtime.h>
#include <stdint.h>
#include <stddef.h>

#define DEV __device__ __forceinline__

typedef __bf16 bf16_t;
typedef bf16_t bf16x8 __attribute__((ext_vector_type(8)));
typedef float f32x4 __attribute__((ext_vector_type(4)));
typedef unsigned short us4 __attribute__((ext_vector_type(4)));
typedef unsigned short us8 __attribute__((ext_vector_type(8)));

// ---------- bf16 <-> f32 helpers (bit-level, RNE) ----------
DEV float bf2f(unsigned short u) {
    union { unsigned int i; float f; } w; w.i = ((unsigned int)u) << 16; return w.f;
}
DEV unsigned short f2bf(float f) {
    union { unsigned int i; float f; } w; w.f = f;
    unsigned int u = w.i;
    return (unsigned short)((u + 0x7fffu + ((u >> 16) & 1u)) >> 16);
}

// ---------- async global -> LDS, 16B per lane ----------
DEV void gl_lds16(const void* g, void* l) {
    __builtin_amdgcn_global_load_lds((const __attribute__((address_space(1))) void*)g,
                                     (__attribute__((address_space(3))) void*)l,
                                     16, 0, 0);
}

// ======================================================================
// prep: z=0..3 -> weight transpose+convert (W fp32 KxN -> WT bf16 NxK)
//       z=4..6 -> activation fp32 -> bf16 convert (q,k,v)
// One dispatch replaces transpose_w + cvt3 (removes one launch bubble).
// ======================================================================
__global__ void __launch_bounds__(256)
prep(const float* __restrict__ W0, const float* __restrict__ W1,
     const float* __restrict__ W2, const float* __restrict__ W3,
     unsigned short* __restrict__ T0, unsigned short* __restrict__ T1,
     unsigned short* __restrict__ T2, unsigned short* __restrict__ T3,
     const float* __restrict__ s0, const float* __restrict__ s1, const float* __restrict__ s2,
     unsigned short* __restrict__ d0, unsigned short* __restrict__ d1, unsigned short* __restrict__ d2) {
    __shared__ float t[32][33];
    int tx = threadIdx.x, ty = threadIdx.y;       // 32 x 8
    int z = blockIdx.z;
    if (z < 4) {
        const float* W    = (z == 0) ? W0 : (z == 1) ? W1 : (z == 2) ? W2 : W3;
        unsigned short* T = (z == 0) ? T0 : (z == 1) ? T1 : (z == 2) ? T2 : T3;
        int k0 = blockIdx.x * 32, n0 = blockIdx.y * 32;
#pragma unroll
        for (int r = 0; r < 4; r++)
            t[ty + r * 8][tx] = W[(size_t)(k0 + ty + r * 8) * 1024 + n0 + tx];
        __syncthreads();
#pragma unroll
        for (int r = 0; r < 4; r++)
            T[(size_t)(n0 + ty + r * 8) * 1024 + k0 + tx] = f2bf(t[tx][ty + r * 8]);
    } else {
        const float* src    = (z == 4) ? s0 : (z == 5) ? s1 : s2;
        unsigned short* dst = (z == 4) ? d0 : (z == 5) ? d1 : d2;
        int tid = ty * 32 + tx;
        int blk = blockIdx.y * 32 + blockIdx.x;   // 0..1023
#pragma unroll
        for (int p = 0; p < 4; p++) {
            int idx = (blk * 256 + tid) * 4 + p * 1048576;
            f32x4 v = *(const f32x4*)&src[idx];
            us4 o;
#pragma unroll
            for (int i = 0; i < 4; i++) o[i] = f2bf(v[i]);
            *(us4*)&dst[idx] = o;
        }
    }
}

// ======================================================================
// Fused Q/K/V projection: z picks (A, Bt, bias, out, mode).
// 128x128 tile, BK=64 (halved barrier/drain count vs BK=32), 4 waves
// each 64x64, mfma 16x16x32 bf16.
// LDS [128][64] bf16 per operand (row stride 128B would be a 2x bank
// conflict on ds_read_b128) -> chunk XOR-swizzle: global source chunk
// kc = kcl ^ (row&7) staged at linear LDS slot kcl; read side applies
// the same XOR. Conflict-free (b128 minimum 8 phases). gl_lds dest
// stays linear (wave-uniform base + lane*16) per rule "both sides or
// neither".
// z=0,1: bf16 split-head (B,H,S,D);  z=2: bf16 (B,H,D,S) for V
// ======================================================================
__global__ void __launch_bounds__(256, 3)
qkv_gemm(const unsigned short* __restrict__ Aq, const unsigned short* __restrict__ Ak,
         const unsigned short* __restrict__ Av,
         const unsigned short* __restrict__ BtQ, const unsigned short* __restrict__ BtK,
         const unsigned short* __restrict__ BtV,
         const float* __restrict__ biq, const float* __restrict__ bik,
         const float* __restrict__ biv,
         unsigned short* __restrict__ Qw, unsigned short* __restrict__ Kw,
         unsigned short* __restrict__ Vtw) {
    const int K = 1024;
    const unsigned short* A  = (blockIdx.z == 0) ? Aq  : (blockIdx.z == 1) ? Ak  : Av;
    const unsigned short* Bt = (blockIdx.z == 0) ? BtQ : (blockIdx.z == 1) ? BtK : BtV;
    const float* bias        = (blockIdx.z == 0) ? biq : (blockIdx.z == 1) ? bik : biv;
    unsigned short* Cout     = (blockIdx.z == 0) ? Qw  : (blockIdx.z == 1) ? Kw  : Vtw;
    const bool vmode = (blockIdx.z == 2);

    __shared__ __align__(16) unsigned short As[128 * 64];
    __shared__ __align__(16) unsigned short Bs[128 * 64];
    int tid = threadIdx.x, lane = tid & 63, wid = tid >> 6;
    int mBase = blockIdx.x * 128, nBase = blockIdx.y * 128;
    int wm = (wid >> 1) * 64, wn = (wid & 1) * 64;
    int c0 = lane & 15, quad = lane >> 4;

    f32x4 acc[4][4] = {};

    for (int k0 = 0; k0 < K; k0 += 64) {
        __syncthreads();
#pragma unroll
        for (int i = 0; i < 4; i++) {
            int cc = i * 256 + tid;            // 1024 chunks of 8 elems
            int row = cc >> 3, kcl = cc & 7;
            int kc = kcl ^ (row & 7);          // inverse-swizzled source
            gl_lds16(A  + (size_t)(mBase + row) * K + k0 + kc * 8, &As[cc * 8]);
            gl_lds16(Bt + (size_t)(nBase + row) * K + k0 + kc * 8, &Bs[cc * 8]);
        }
        __syncthreads();
#pragma unroll
        for (int kk = 0; kk < 2; kk++) {
            bf16x8 af[4], bfr[4];
#pragma unroll
            for (int t = 0; t < 4; t++) {
                int ra = wm + t * 16 + c0;
                int rb = wn + t * 16 + c0;
                af[t]  = *(const bf16x8*)&As[ra * 64 + (((quad + 4 * kk) ^ (ra & 7)) << 3)];
                bfr[t] = *(const bf16x8*)&Bs[rb * 64 + (((quad + 4 * kk) ^ (rb & 7)) << 3)];
            }
#pragma unroll
            for (int mt = 0; mt < 4; mt++)
#pragma unroll
                for (int nt = 0; nt < 4; nt++)
                    acc[mt][nt] = __builtin_amdgcn_mfma_f32_16x16x32_bf16(af[mt], bfr[nt], acc[mt][nt], 0, 0, 0);
        }
    }

    // C/D layout: col = lane&15, row = quad*4 + reg
#pragma unroll
    for (int mt = 0; mt < 4; mt++) {
#pragma unroll
        for (int nt = 0; nt < 4; nt++) {
            int n = nBase + wn + nt * 16 + c0;
            float bv = bias[n];
            if (vmode) {
                int m0 = mBase + wm + mt * 16 + quad * 4;
                int b = m0 >> 10, s = m0 & 1023, h = n >> 6, d = n & 63;
                us4 pk;
#pragma unroll
                for (int r = 0; r < 4; r++) pk[r] = f2bf(acc[mt][nt][r] + bv);
                *(us4*)&Cout[((size_t)((b * 16 + h) * 64 + d)) * 1024 + s] = pk;
            } else {
#pragma unroll
                for (int r = 0; r < 4; r++) {
                    int m = mBase + wm + mt * 16 + quad * 4 + r;
                    int b = m >> 10, s = m & 1023, h = n >> 6, d = n & 63;
                    Cout[((size_t)((b * 16 + h) * 1024 + s)) * 64 + d] = f2bf(acc[mt][nt][r] + bv);
                }
            }
        }
    }
}

// ======================================================================
// Final projection: C = ctx @ WoT^T + bo -> fp32 (M,1024)
// Same BK=64 + chunk-XOR-swizzle structure as qkv_gemm.
// ======================================================================
__global__ void __launch_bounds__(256, 3)
out_gemm(const unsigned short* __restrict__ A,
         const unsigned short* __restrict__ Bt,
         const float* __restrict__ bias,
         float* __restrict__ Cout) {
    const int K = 1024;
    __shared__ __align__(16) unsigned short As[128 * 64];
    __shared__ __align__(16) unsigned short Bs[128 * 64];
    int tid = threadIdx.x, lane = tid & 63, wid = tid >> 6;
    int mBase = blockIdx.x * 128, nBase = blockIdx.y * 128;
    int wm = (wid >> 1) * 64, wn = (wid & 1) * 64;
    int c0 = lane & 15, quad = lane >> 4;

    f32x4 acc[4][4] = {};

    for (int k0 = 0; k0 < K; k0 += 64) {
        __syncthreads();
#pragma unroll
        for (int i = 0; i < 4; i++) {
            int cc = i * 256 + tid;
            int row = cc >> 3, kcl = cc & 7;
            int kc = kcl ^ (row & 7);
            gl_lds16(A  + (size_t)(mBase + row) * K + k0 + kc * 8, &As[cc * 8]);
            gl_lds16(Bt + (size_t)(nBase + row) * K + k0 + kc * 8, &Bs[cc * 8]);
        }
        __syncthreads();
#pragma unroll
        for (int kk = 0; kk < 2; kk++) {
            bf16x8 af[4], bfr[4];
#pragma unroll
            for (int t = 0; t < 4; t++) {
                int ra = wm + t * 16 + c0;
                int rb = wn + t * 16 + c0;
                af[t]  = *(const bf16x8*)&As[ra * 64 + (((quad + 4 * kk) ^ (ra & 7)) << 3)];
                bfr[t] = *(const bf16x8*)&Bs[rb * 64 + (((quad + 4 * kk) ^ (rb & 7)) << 3)];
            }
#pragma unroll
            for (int mt = 0; mt < 4; mt++)
#pragma unroll
                for (int nt = 0; nt < 4; nt++)
                    acc[mt][nt] = __builtin_amdgcn_mfma_f32_16x16x32_bf16(af[mt], bfr[nt], acc[mt][nt], 0, 0, 0);
        }
    }
#pragma unroll
    for (int mt = 0; mt < 4; mt++)
#pragma unroll
        for (int nt = 0; nt < 4; nt++) {
            int n = nBase + wn + nt * 16 + c0;
            float bv = bias[n];
#pragma unroll
            for (int r = 0; r < 4; r++) {
                int m = mBase + wm + mt * 16 + quad * 4 + r;
                Cout[(size_t)m * 1024 + n] = acc[mt][nt][r] + bv;
            }
        }
}

// ======================================================================
// Fused QK^T/64 + mask + softmax + attn-write (fp32) + PV -> ctx (bf16)
// One block = 16 q-rows of one (b,h).  [unchanged from round 3]
// ======================================================================
__global__ void __launch_bounds__(256, 3)
attn_pv(const unsigned short* __restrict__ Qws,
        const unsigned short* __restrict__ Kws,
        const unsigned short* __restrict__ Vtw,
        const float* __restrict__ maskp,
        float* __restrict__ attnOut,
        unsigned short* __restrict__ ctx) {
    __shared__ __align__(16) unsigned short ldsP[17408]; // Ks chunk (256x64) / P_lds (4*16*272)
    __shared__ float redbuf[4][16];

    int tid = threadIdx.x, lane = tid & 63, wid = tid >> 6;
    int c0 = lane & 15, quad = lane >> 4;
    int bh = blockIdx.y, b = bh >> 4, h = bh & 15;
    int q0 = blockIdx.x * 16;

    // Q A-fragments
    bf16x8 aq0, aq1;
    {
        const unsigned short* qp = Qws + ((size_t)bh * 1024 + q0 + c0) * 64 + quad * 8;
        aq0 = *(const bf16x8*)qp;
        aq1 = *(const bf16x8*)(qp + 32);
    }

    f32x4 acc[16] = {};

    // ---- Phase 1: QK^T (K staged via gl_lds, 4 chunks of 256 rows) ----
    for (int ch = 0; ch < 4; ch++) {
        __syncthreads();
#pragma unroll
        for (int i = 0; i < 8; i++) {
            int cb = wid * 64 + 256 * i;
            int cc = cb + lane;
            int row = cc >> 3, kc = cc & 7;
            gl_lds16(Kws + ((size_t)bh * 1024 + ch * 256 + row) * 64 + kc * 8, &ldsP[cb * 8]);
        }
        __syncthreads();
#pragma unroll
        for (int nt = 0; nt < 4; nt++) {
            int srow = wid * 64 + nt * 16 + c0;
            const unsigned short* kp = &ldsP[srow * 64 + quad * 8];
            bf16x8 b0 = *(const bf16x8*)kp;
            bf16x8 b1 = *(const bf16x8*)(kp + 32);
            int ai = ch * 4 + nt;
            acc[ai] = __builtin_amdgcn_mfma_f32_16x16x32_bf16(aq0, b0, acc[ai], 0, 0, 0);
            acc[ai] = __builtin_amdgcn_mfma_f32_16x16x32_bf16(aq1, b1, acc[ai], 0, 0, 0);
        }
    }

    // ---- Phase 2: softmax ----
    float lmax[4] = {-3e38f, -3e38f, -3e38f, -3e38f};
#pragma unroll
    for (int i = 0; i < 16; i++) {
        int col = (i >> 2) * 256 + wid * 64 + (i & 3) * 16 + c0;
        float mval = maskp[b * 1024 + col] * (-1e9f);
#pragma unroll
        for (int r = 0; r < 4; r++) {
            float v = acc[i][r] * (1.0f / 64.0f) + mval;
            acc[i][r] = v;
            lmax[r] = fmaxf(lmax[r], v);
        }
    }
#pragma unroll
    for (int st = 1; st < 16; st <<= 1) {
#pragma unroll
        for (int r = 0; r < 4; r++) lmax[r] = fmaxf(lmax[r], __shfl_xor(lmax[r], st, 64));
    }
    if (c0 == 0) {
#pragma unroll
        for (int r = 0; r < 4; r++) redbuf[wid][quad * 4 + r] = lmax[r];
    }
    __syncthreads();   // also guarantees all QK^T MFMAs done reading ldsP
    float rmax[4];
#pragma unroll
    for (int r = 0; r < 4; r++) {
        int row = quad * 4 + r;
        rmax[r] = fmaxf(fmaxf(redbuf[0][row], redbuf[1][row]), fmaxf(redbuf[2][row], redbuf[3][row]));
    }
    float lsum[4] = {0.f, 0.f, 0.f, 0.f};
#pragma unroll
    for (int i = 0; i < 16; i++) {
#pragma unroll
        for (int r = 0; r < 4; r++) {
            float e = __expf(acc[i][r] - rmax[r]);
            acc[i][r] = e;
            lsum[r] += e;
        }
    }
#pragma unroll
    for (int st = 1; st < 16; st <<= 1) {
#pragma unroll
        for (int r = 0; r < 4; r++) lsum[r] += __shfl_xor(lsum[r], st, 64);
    }
    __syncthreads();
    if (c0 == 0) {
#pragma unroll
        for (int r = 0; r < 4; r++) redbuf[wid][quad * 4 + r] = lsum[r];
    }
    __syncthreads();
    float rinv[4];
#pragma unroll
    for (int r = 0; r < 4; r++) {
        int row = quad * 4 + r;
        rinv[r] = 1.0f / (redbuf[0][row] + redbuf[1][row] + redbuf[2][row] + redbuf[3][row]);
    }

    // ---- Phase 3: attn global write (fp32) + P -> LDS (bf16, A-layout) ----
    size_t gbase = ((size_t)bh * 1024 + q0) * 1024;
#pragma unroll
    for (int i = 0; i < 16; i++) {
        int kk = (i >> 2) * 64 + (i & 3) * 16 + c0;
        int col = (i >> 2) * 256 + wid * 64 + (i & 3) * 16 + c0;
        int kks = kk ^ (quad << 3);   // row>>2 == quad for all 4 regs
#pragma unroll
        for (int r = 0; r < 4; r++) {
            int row = quad * 4 + r;
            float pv = acc[i][r] * rinv[r];
            attnOut[gbase + (size_t)row * 1024 + col] = pv;
            ldsP[wid * 4352 + row * 272 + kks] = f2bf(pv);
        }
    }

    // ---- Phase 4: PV (V direct from global/L2, 1-chunk-ahead prefetch) ----
    const unsigned short* vbase = Vtw + ((size_t)(bh * 64 + wid * 16 + c0)) * 1024 + quad * 8;
    bf16x8 vcur[8], vnxt[8];
#pragma unroll
    for (int j = 0; j < 8; j++)
        vcur[j] = *(const bf16x8*)&vbase[(j >> 1) * 64 + (j & 1) * 32];   // ch=0 frags
    __syncthreads();   // P_lds ready (cross-wave)

    f32x4 ctx0 = {}, ctx1 = {};
#pragma unroll
    for (int ch = 0; ch < 4; ch++) {
        if (ch < 3) {
#pragma unroll
            for (int j = 0; j < 8; j++)
                vnxt[j] = *(const bf16x8*)&vbase[(ch + 1) * 256 + (j >> 1) * 64 + (j & 1) * 32];
        }
#pragma unroll
        for (int wv = 0; wv < 4; wv++) {
            int kidx0 = (ch * 64 + quad * 8) ^ ((c0 >> 2) << 3);
            int kidx1 = (ch * 64 + 32 + quad * 8) ^ ((c0 >> 2) << 3);
            bf16x8 a0 = *(const bf16x8*)&ldsP[wv * 4352 + c0 * 272 + kidx0];
            bf16x8 a1 = *(const bf16x8*)&ldsP[wv * 4352 + c0 * 272 + kidx1];
            ctx0 = __builtin_amdgcn_mfma_f32_16x16x32_bf16(a0, vcur[wv * 2 + 0], ctx0, 0, 0, 0);
            ctx1 = __builtin_amdgcn_mfma_f32_16x16x32_bf16(a1, vcur[wv * 2 + 1], ctx1, 0, 0, 0);
        }
#pragma unroll
        for (int j = 0; j < 8; j++) vcur[j] = vnxt[j];
    }
    f32x4 ctxacc = ctx0 + ctx1;

    // ctx write: C-layout frag, rows=q, cols = wid*16+c0 (d)
#pragma unroll
    for (int r = 0; r < 4; r++) {
        int s = q0 + quad * 4 + r;
        ctx[((size_t)(b * 1024 + s)) * 1024 + h * 64 + wid * 16 + c0] = f2bf(ctxacc[r]);
    }
}

// ======================================================================
// host
// ======================================================================
extern "C" void kernel_launch(void* const* d_in, const int* in_sizes, int n_in,
                              void* d_out, int out_size, void* d_ws, size_t ws_size,
                              hipStream_t stream) {
    (void)in_sizes; (void)n_in; (void)out_size; (void)ws_size;
    const float* q    = (const float*)d_in[0];
    const float* k    = (const float*)d_in[1];
    const float* v    = (const float*)d_in[2];
    const float* mask = (const float*)d_in[3];
    const float* Wq   = (const float*)d_in[4];
    const float* bq   = (const float*)d_in[5];
    const float* Wk   = (const float*)d_in[6];
    const float* bk   = (const float*)d_in[7];
    const float* Wv   = (const float*)d_in[8];
    const float* bv   = (const float*)d_in[9];
    const float* Wo   = (const float*)d_in[10];
    const float* bo   = (const float*)d_in[11];

    float* outF  = (float*)d_out;                          // (B,S,1024): 4M floats
    float* attnF = outF + (size_t)4 * 1024 * 1024;         // (B,H,S,S): 64M floats

    unsigned short* wsu = (unsigned short*)d_ws;
    const size_t M1 = (size_t)1024 * 1024;
    unsigned short* WqT = wsu + 0 * M1;
    unsigned short* WkT = wsu + 1 * M1;
    unsigned short* WvT = wsu + 2 * M1;
    unsigned short* WoT = wsu + 3 * M1;
    unsigned short* tq  = wsu + 4 * M1;        // 4M each
    unsigned short* tk  = wsu + 8 * M1;
    unsigned short* tv  = wsu + 12 * M1;
    unsigned short* Qw  = wsu + 16 * M1;       // (B,H,S,D)
    unsigned short* Kw  = wsu + 20 * M1;
    unsigned short* Vtw = wsu + 24 * M1;       // (B,H,D,S)
    unsigned short* ctx = wsu + 28 * M1;       // (B,S,H*D)  -> 64MB total

    prep<<<dim3(32, 32, 7), dim3(32, 8), 0, stream>>>(Wq, Wk, Wv, Wo, WqT, WkT, WvT, WoT,
                                                      q, k, v, tq, tk, tv);

    qkv_gemm<<<dim3(32, 8, 3), 256, 0, stream>>>(tq, tk, tv, WqT, WkT, WvT, bq, bk, bv, Qw, Kw, Vtw);

    attn_pv<<<dim3(64, 64), 256, 0, stream>>>(Qw, Kw, Vtw, mask, attnF, ctx);

    out_gemm<<<dim3(32, 8), 256, 0, stream>>>(ctx, WoT, bo, outF);
}